// Round 7
// baseline (458.172 us; speedup 1.0000x reference)
//
#include <hip/hip_runtime.h>

#define GN 16384
#define GD 128
#define GH 512
#define GK 16384

#define BM 64
#define BK 128
#define PADK 136            // LDS row stride in shorts

typedef __attribute__((ext_vector_type(8))) short s8v;   // 8 x bf16 (as short)
typedef __attribute__((ext_vector_type(4))) float f4v;
typedef __attribute__((ext_vector_type(4))) int   i4v;

static __device__ inline unsigned short f2bf(float f) {
  union { float f; unsigned u; } a; a.f = f;
  unsigned r = a.u + 0x7fffu + ((a.u >> 16) & 1u);   // RNE
  return (unsigned short)(r >> 16);
}

static __device__ inline float waveAllSum(float v) {
  #pragma unroll
  for (int off = 32; off; off >>= 1) v += __shfl_xor(v, off);
  return v;
}

// ---------------- kernel 1: L = log_map_zero(exp_map_zero(x)) ----------------
__global__ void k_logmap(const float* __restrict__ x, float* __restrict__ Lf) {
  int row  = (blockIdx.x << 2) + (threadIdx.x >> 6);
  int lane = threadIdx.x & 63;
  size_t base = ((size_t)row << 7) + (lane << 1);
  float2 v = *(const float2*)(x + base);
  float a0 = (lane == 0) ? 0.f : v.x;   // u[...,0] is ignored by exp_map
  float a1 = v.y;
  float n = fmaxf(sqrtf(waveAllSum(a0*a0 + a1*a1)), 1e-7f);
  float sh = sinhf(n), ch = coshf(n);
  float y0 = sh * a0 / n, y1 = sh * a1 / n;        // h[...,1:]
  float ny = fmaxf(sqrtf(waveAllSum(y0*y0 + y1*y1)), 1e-7f);
  float z  = fmaxf(ch, 1.f + 1e-7f);
  float th = logf(z + sqrtf(z*z - 1.f));           // arcosh(h0)
  float l0 = th * y0 / ny;
  float l1 = th * y1 / ny;
  if (lane == 0) l0 = 0.f;                         // L[...,0] = 0
  *(float2*)(Lf + base) = make_float2(l0, l1);
}

// -------- generic 64x64 tiled transpose+bf16: dst[c][r] = bf16(src[r][c]) ---
__global__ void k_tconv(const float* __restrict__ src, unsigned short* __restrict__ dst,
                        int NR, int NC) {
  __shared__ float tile[64][65];
  const int r0 = blockIdx.x << 6;
  const int c0 = blockIdx.y << 6;
  const int t  = threadIdx.x;
  const int r  = t >> 2;
  const int cg = (t & 3) << 4;
  const float* s = src + (size_t)(r0 + r) * NC + c0 + cg;
  #pragma unroll
  for (int j = 0; j < 4; ++j) {
    float4 f = ((const float4*)s)[j];
    tile[r][cg + 4*j + 0] = f.x;
    tile[r][cg + 4*j + 1] = f.y;
    tile[r][cg + 4*j + 2] = f.z;
    tile[r][cg + 4*j + 3] = f.w;
  }
  __syncthreads();
  s8v o0, o1;
  #pragma unroll
  for (int j = 0; j < 8; ++j) o0[j] = (short)f2bf(tile[cg + j][r]);
  #pragma unroll
  for (int j = 0; j < 8; ++j) o1[j] = (short)f2bf(tile[cg + 8 + j][r]);
  unsigned short* d = dst + (size_t)(c0 + r) * NR + r0 + cg;
  *(s8v*)d = o0;
  *((s8v*)d + 1) = o1;
}

// ---------------- kernel 3: M = adj @ L  (bf16 MFMA, f32 accumulate) --------
// R1's proven-streaming structure (BM=64, BK=128, 512 thr = 8 waves 2Mx4N).
// adj loads are NONTEMPORAL (evict-first) so the 1.07 GB A-stream does not
// evict the 4 MB Lt panel from each XCD's L2; B then hits L2 (~34 TB/s) and
// its HBM traffic is ~4 MB per XCD. Mout stores also nt.
__global__ __launch_bounds__(512) void k_gemm(const float* __restrict__ adj,
    const unsigned short* __restrict__ Lt, float* __restrict__ Mout) {
  __shared__ __align__(16) short As[BM * PADK];
  __shared__ __align__(16) short Bs[128 * PADK];
  const int tid  = threadIdx.x;
  const int lane = tid & 63, wid = tid >> 6;
  const int wr = wid >> 2, wc = wid & 3;
  const size_t blockRow = (size_t)blockIdx.x * BM;

  f4v acc[2][2];
  #pragma unroll
  for (int i = 0; i < 2; ++i)
    #pragma unroll
    for (int j = 0; j < 2; ++j) acc[i][j] = (f4v){0.f, 0.f, 0.f, 0.f};

  // staging maps
  const int arow = tid >> 3, acol = (tid & 7) << 4;        // 64 rows x 128 k (f32)
  const float* ap = adj + (blockRow + arow) * (size_t)GK + acol;
  const int brow = tid >> 2, bkg = (tid & 3) << 5;         // 128 d-rows x 128 k (bf16)
  const unsigned short* bp = Lt + (size_t)brow * GK + bkg;

  const int aoff = arow * PADK + acol;
  const int boff = brow * PADK + bkg;
  const int afrag = (32*wr + (lane & 15)) * PADK + ((lane >> 4) << 3);
  const int bfrag = (32*wc + (lane & 15)) * PADK + ((lane >> 4) << 3);

  f4v  ra[4];
  i4v  rb[4];
  #pragma unroll
  for (int j = 0; j < 4; ++j) ra[j] = __builtin_nontemporal_load((const f4v*)ap + j);
  #pragma unroll
  for (int j = 0; j < 4; ++j) rb[j] = ((const i4v*)bp)[j];

  const int NIT = GK / BK;   // 128
  for (int it = 0; it < NIT; ++it) {
    // write staged tile to LDS (convert adj f32 -> bf16)
    s8v s0, s1;
    s0[0]=(short)f2bf(ra[0][0]); s0[1]=(short)f2bf(ra[0][1]); s0[2]=(short)f2bf(ra[0][2]); s0[3]=(short)f2bf(ra[0][3]);
    s0[4]=(short)f2bf(ra[1][0]); s0[5]=(short)f2bf(ra[1][1]); s0[6]=(short)f2bf(ra[1][2]); s0[7]=(short)f2bf(ra[1][3]);
    s1[0]=(short)f2bf(ra[2][0]); s1[1]=(short)f2bf(ra[2][1]); s1[2]=(short)f2bf(ra[2][2]); s1[3]=(short)f2bf(ra[2][3]);
    s1[4]=(short)f2bf(ra[3][0]); s1[5]=(short)f2bf(ra[3][1]); s1[6]=(short)f2bf(ra[3][2]); s1[7]=(short)f2bf(ra[3][3]);
    *(s8v*)&As[aoff]     = s0;
    *(s8v*)&As[aoff + 8] = s1;
    #pragma unroll
    for (int j = 0; j < 4; ++j) *(i4v*)&Bs[boff + 8*j] = rb[j];
    __syncthreads();

    if (it + 1 < NIT) {           // prefetch next tile into registers
      const float* ap2 = ap + (size_t)(it + 1) * BK;
      const unsigned short* bp2 = bp + (size_t)(it + 1) * BK;
      #pragma unroll
      for (int j = 0; j < 4; ++j) ra[j] = __builtin_nontemporal_load((const f4v*)ap2 + j);
      #pragma unroll
      for (int j = 0; j < 4; ++j) rb[j] = ((const i4v*)bp2)[j];
    }

    #pragma unroll
    for (int kk = 0; kk < 128; kk += 32) {
      s8v a0 = *(const s8v*)&As[afrag + kk];
      s8v a1 = *(const s8v*)&As[afrag + 16*PADK + kk];
      s8v b0 = *(const s8v*)&Bs[bfrag + kk];
      s8v b1 = *(const s8v*)&Bs[bfrag + 16*PADK + kk];
      acc[0][0] = __builtin_amdgcn_mfma_f32_16x16x32_bf16(a0, b0, acc[0][0], 0, 0, 0);
      acc[0][1] = __builtin_amdgcn_mfma_f32_16x16x32_bf16(a0, b1, acc[0][1], 0, 0, 0);
      acc[1][0] = __builtin_amdgcn_mfma_f32_16x16x32_bf16(a1, b0, acc[1][0], 0, 0, 0);
      acc[1][1] = __builtin_amdgcn_mfma_f32_16x16x32_bf16(a1, b1, acc[1][1], 0, 0, 0);
    }
    __syncthreads();
  }

  // epilogue: C/D layout col = lane&15, row = (lane>>4)*4 + r
  #pragma unroll
  for (int mi = 0; mi < 2; ++mi)
    #pragma unroll
    for (int ni = 0; ni < 2; ++ni) {
      size_t r0 = blockRow + 32*wr + 16*mi + ((lane >> 4) << 2);
      int    c0 = 32*wc + 16*ni + (lane & 15);
      #pragma unroll
      for (int r2 = 0; r2 < 4; ++r2)
        __builtin_nontemporal_store(acc[mi][ni][r2], &Mout[(r0 + r2) * GD + c0]);
    }
}

// ------- kernel 4: out = exp(log(exp(M)) + L), emitted directly as bf16 -----
__global__ void k_maps(const float* __restrict__ Mv, const float* __restrict__ Lf,
                       unsigned short* __restrict__ outB) {
  int row  = (blockIdx.x << 2) + (threadIdx.x >> 6);
  int lane = threadIdx.x & 63;
  size_t base = ((size_t)row << 7) + (lane << 1);
  float2 mv = *(const float2*)(Mv + base);
  float2 lv = *(const float2*)(Lf + base);
  float v0 = (lane == 0) ? 0.f : mv.x;
  float v1 = mv.y;
  float nv = fmaxf(sqrtf(waveAllSum(v0*v0 + v1*v1)), 1e-7f);
  float ch = coshf(nv), sh = sinhf(nv);
  float g0 = sh * v0 / nv, g1 = sh * v1 / nv;          // agg[...,1:]
  float ny = fmaxf(sqrtf(waveAllSum(g0*g0 + g1*g1)), 1e-7f);
  float z  = fmaxf(ch, 1.f + 1e-7f);
  float th = logf(z + sqrtf(z*z - 1.f));
  float la0 = th * g0 / ny, la1 = th * g1 / ny;        // log_map(agg)
  float s0 = la0 + lv.x, s1 = la1 + lv.y;              // + (1+eps)*L
  if (lane == 0) s0 = 0.f;
  float ns  = fmaxf(sqrtf(waveAllSum(s0*s0 + s1*s1)), 1e-7f);
  float ch2 = coshf(ns), sh2 = sinhf(ns);
  float o0 = sh2 * s0 / ns, o1 = sh2 * s1 / ns;
  if (lane == 0) o0 = ch2;                             // out[...,0] = cosh
  unsigned pack = (unsigned)f2bf(o0) | ((unsigned)f2bf(o1) << 16);
  *(unsigned*)(outB + base) = pack;
}

// ---- kernel 5: T = relu(out@W1 + b1) @ W2 + b2  (bf16 MFMA, f32 accum) -----
#define PAD1 136
#define PADH 520
__global__ __launch_bounds__(256, 2) void k_mlp(const unsigned short* __restrict__ outB,
    const unsigned short* __restrict__ W1t, const float* __restrict__ b1,
    const unsigned short* __restrict__ W2t, const float* __restrict__ b2,
    float* __restrict__ Tout) {
  __shared__ __align__(16) short sA[32 * PAD1];
  __shared__ __align__(16) short sH[32 * PADH];
  const int tid  = threadIdx.x;
  const int lane = tid & 63, wc = tid >> 6;
  const int row0 = blockIdx.x << 5;

  {
    const int r = tid >> 3, cg = (tid & 7) << 4;
    const unsigned short* src = outB + (size_t)(row0 + r) * GD + cg;
    i4v v0 = ((const i4v*)src)[0];
    i4v v1 = ((const i4v*)src)[1];
    *(i4v*)&sA[r * PAD1 + cg]     = v0;
    *(i4v*)&sA[r * PAD1 + cg + 8] = v1;
  }
  __syncthreads();

  f4v acc1[2][8];
  #pragma unroll
  for (int mi = 0; mi < 2; ++mi)
    #pragma unroll
    for (int ni = 0; ni < 8; ++ni) acc1[mi][ni] = (f4v){0.f,0.f,0.f,0.f};

  const int afr = (lane & 15) * PAD1 + ((lane >> 4) << 3);
  #pragma unroll
  for (int kk = 0; kk < 4; ++kk) {                   // K = 128 d
    s8v a0 = *(const s8v*)&sA[afr + kk*32];
    s8v a1 = *(const s8v*)&sA[afr + 16*PAD1 + kk*32];
    #pragma unroll
    for (int ni = 0; ni < 8; ++ni) {
      const unsigned short* bp = W1t + (size_t)(128*wc + 16*ni + (lane & 15)) * GD
                                 + ((lane >> 4) << 3) + kk*32;
      s8v b = *(const s8v*)bp;
      acc1[0][ni] = __builtin_amdgcn_mfma_f32_16x16x32_bf16(a0, b, acc1[0][ni], 0, 0, 0);
      acc1[1][ni] = __builtin_amdgcn_mfma_f32_16x16x32_bf16(a1, b, acc1[1][ni], 0, 0, 0);
    }
  }
  #pragma unroll
  for (int ni = 0; ni < 8; ++ni) {
    int col = 128*wc + 16*ni + (lane & 15);
    float bb = b1[col];
    #pragma unroll
    for (int mi = 0; mi < 2; ++mi) {
      #pragma unroll
      for (int j = 0; j < 4; ++j) {
        int row = 16*mi + ((lane >> 4) << 2) + j;
        float v = fmaxf(acc1[mi][ni][j] + bb, 0.f);
        sH[row * PADH + col] = (short)f2bf(v);
      }
    }
  }
  __syncthreads();

  f4v acc2[2][2];
  #pragma unroll
  for (int mi = 0; mi < 2; ++mi)
    #pragma unroll
    for (int ni = 0; ni < 2; ++ni) acc2[mi][ni] = (f4v){0.f,0.f,0.f,0.f};

  const int hfr = (lane & 15) * PADH + ((lane >> 4) << 3);
  #pragma unroll
  for (int kk = 0; kk < 16; ++kk) {                  // K = 512 h
    s8v a0 = *(const s8v*)&sH[hfr + kk*32];
    s8v a1 = *(const s8v*)&sH[hfr + 16*PADH + kk*32];
    #pragma unroll
    for (int ni = 0; ni < 2; ++ni) {
      const unsigned short* bp = W2t + (size_t)(32*wc + 16*ni + (lane & 15)) * GH
                                 + ((lane >> 4) << 3) + kk*32;
      s8v b = *(const s8v*)bp;
      acc2[0][ni] = __builtin_amdgcn_mfma_f32_16x16x32_bf16(a0, b, acc2[0][ni], 0, 0, 0);
      acc2[1][ni] = __builtin_amdgcn_mfma_f32_16x16x32_bf16(a1, b, acc2[1][ni], 0, 0, 0);
    }
  }
  #pragma unroll
  for (int mi = 0; mi < 2; ++mi)
    #pragma unroll
    for (int ni = 0; ni < 2; ++ni) {
      int c0 = 32*wc + 16*ni + (lane & 15);
      float bb = b2[c0];
      size_t r0 = row0 + 16*mi + ((lane >> 4) << 2);
      #pragma unroll
      for (int j = 0; j < 4; ++j)
        Tout[(r0 + j) * GD + c0] = acc2[mi][ni][j] + bb;
    }
}

extern "C" void kernel_launch(void* const* d_in, const int* in_sizes, int n_in,
                              void* d_out, int out_size, void* d_ws, size_t ws_size,
                              hipStream_t stream) {
  const float* x   = (const float*)d_in[0];
  const float* adj = (const float*)d_in[1];
  const float* W1  = (const float*)d_in[2];
  const float* b1  = (const float*)d_in[3];
  const float* W2  = (const float*)d_in[4];
  const float* b2  = (const float*)d_in[5];
  float* Tout = (float*)d_out;

  char* ws = (char*)d_ws;
  float*          Lf   = (float*)ws;                               // [0, 8MB)
  unsigned short* Lt   = (unsigned short*)(ws + (8u  << 20));      // [8MB, 12MB)
  float*          Mv   = (float*)(ws + (12u << 20));               // [12MB, 20MB)
  unsigned short* outB = (unsigned short*)(ws + (20u << 20));      // [20MB, 24MB)
  unsigned short* W1t  = (unsigned short*)(ws + (24u << 20));               // 128 KB
  unsigned short* W2t  = (unsigned short*)(ws + (24u << 20) + (128u << 10)); // 128 KB

  k_logmap <<<GN / 4, 256, 0, stream>>>(x, Lf);
  k_tconv  <<<dim3(GK / 64, GD / 64), 256, 0, stream>>>(Lf, Lt, GN, GD);   // L -> Lt[d][k]
  k_tconv  <<<dim3(GD / 64, GH / 64), 256, 0, stream>>>(W1, W1t, GD, GH);  // W1 -> W1t[h][d]
  k_tconv  <<<dim3(GH / 64, GD / 64), 256, 0, stream>>>(W2, W2t, GH, GD);  // W2 -> W2t[d][h]
  k_gemm   <<<GN / BM, 512, 0, stream>>>(adj, Lt, Mv);
  k_maps   <<<GN / 4, 256, 0, stream>>>(Mv, Lf, outB);
  k_mlp    <<<GN / 32, 256, 0, stream>>>(outB, W1t, b1, W2t, b2, Tout);
}

// Round 8
// 274.711 us; speedup vs baseline: 1.6678x; 1.6678x over previous
//
#include <hip/hip_runtime.h>

#define GN 16384
#define GD 128
#define GH 512
#define GK 16384

#define SPLITS 4
#define SKK (GK / SPLITS)   // 4096 k per split
#define BM 128
#define BK 64

typedef __attribute__((ext_vector_type(8))) short s8v;   // 8 x bf16 (as short)
typedef __attribute__((ext_vector_type(4))) float f4v;
typedef __attribute__((ext_vector_type(4))) int   i4v;

#define AS1 __attribute__((address_space(1)))
#define AS3 __attribute__((address_space(3)))

static __device__ inline unsigned short f2bf(float f) {
  union { float f; unsigned u; } a; a.f = f;
  unsigned r = a.u + 0x7fffu + ((a.u >> 16) & 1u);   // RNE
  return (unsigned short)(r >> 16);
}

static __device__ inline unsigned cvtpk(float lo, float hi) {
  unsigned r;
  asm("v_cvt_pk_bf16_f32 %0, %1, %2" : "=v"(r) : "v"(lo), "v"(hi));
  return r;
}

static __device__ inline float waveAllSum(float v) {
  #pragma unroll
  for (int off = 32; off; off >>= 1) v += __shfl_xor(v, off);
  return v;
}

// ---------------- kernel 1: L = log_map_zero(exp_map_zero(x)) ----------------
__global__ void k_logmap(const float* __restrict__ x, float* __restrict__ Lf) {
  int row  = (blockIdx.x << 2) + (threadIdx.x >> 6);
  int lane = threadIdx.x & 63;
  size_t base = ((size_t)row << 7) + (lane << 1);
  float2 v = *(const float2*)(x + base);
  float a0 = (lane == 0) ? 0.f : v.x;   // u[...,0] is ignored by exp_map
  float a1 = v.y;
  float n = fmaxf(sqrtf(waveAllSum(a0*a0 + a1*a1)), 1e-7f);
  float sh = sinhf(n), ch = coshf(n);
  float y0 = sh * a0 / n, y1 = sh * a1 / n;        // h[...,1:]
  float ny = fmaxf(sqrtf(waveAllSum(y0*y0 + y1*y1)), 1e-7f);
  float z  = fmaxf(ch, 1.f + 1e-7f);
  float th = logf(z + sqrtf(z*z - 1.f));           // arcosh(h0)
  float l0 = th * y0 / ny;
  float l1 = th * y1 / ny;
  if (lane == 0) l0 = 0.f;                         // L[...,0] = 0
  *(float2*)(Lf + base) = make_float2(l0, l1);
}

// -------- generic 64x64 tiled transpose+bf16: dst[c][r] = bf16(src[r][c]) ---
__global__ void k_tconv(const float* __restrict__ src, unsigned short* __restrict__ dst,
                        int NR, int NC) {
  __shared__ float tile[64][65];
  const int r0 = blockIdx.x << 6;
  const int c0 = blockIdx.y << 6;
  const int t  = threadIdx.x;
  const int r  = t >> 2;
  const int cg = (t & 3) << 4;
  const float* s = src + (size_t)(r0 + r) * NC + c0 + cg;
  #pragma unroll
  for (int j = 0; j < 4; ++j) {
    float4 f = ((const float4*)s)[j];
    tile[r][cg + 4*j + 0] = f.x;
    tile[r][cg + 4*j + 1] = f.y;
    tile[r][cg + 4*j + 2] = f.z;
    tile[r][cg + 4*j + 3] = f.w;
  }
  __syncthreads();
  s8v o0, o1;
  #pragma unroll
  for (int j = 0; j < 8; ++j) o0[j] = (short)f2bf(tile[cg + j][r]);
  #pragma unroll
  for (int j = 0; j < 8; ++j) o1[j] = (short)f2bf(tile[cg + 8 + j][r]);
  unsigned short* d = dst + (size_t)(c0 + r) * NR + r0 + cg;
  *(s8v*)d = o0;
  *((s8v*)d + 1) = o1;
}

// ----- kernel 3: Mpart[s] = adj[:, s] @ L[s, :]  (bf16 MFMA, f32 accum) -----
// m97-style: global_load_lds staging (A as f32, B bf16), single-buffered,
// 2-barrier loop. XOR-swizzled 16B granules (inverse swizzle on the GLOBAL
// source, swizzle on the LDS read — both-sides rule). A converted f32->bf16
// at fragment-read time via v_cvt_pk_bf16_f32. BM=128, BK=64, 512 thr =
// 8 waves (2M x 4N), wave tile 64x32. Split-K=4: split = bid&3.
__global__ __launch_bounds__(512) void k_gemm(const float* __restrict__ adj,
    const unsigned short* __restrict__ Lt, float* __restrict__ Mpart) {
  __shared__ __align__(16) float          As[BM * BK];    // 32 KB
  __shared__ __align__(16) unsigned short Bs[128 * BK];   // 16 KB
  const int tid  = threadIdx.x;
  const int lane = tid & 63, wid = tid >> 6;
  const int wr = wid >> 2, wn = wid & 3;
  const int l15 = lane & 15, lhi = (lane >> 4) << 3;
  const int bid = blockIdx.x;
  const int split = bid & 3, rowblk = bid >> 2;
  const size_t blockRow = (size_t)rowblk * BM;
  const size_t k0 = (size_t)split * SKK;

  f4v acc[4][2];
  #pragma unroll
  for (int m = 0; m < 4; ++m)
    #pragma unroll
    for (int n = 0; n < 2; ++n) acc[m][n] = (f4v){0.f, 0.f, 0.f, 0.f};

  // A staging: thread -> row rA = tid>>4 (+32 per j), granule gA = tid&15.
  // LDS slot (row, g) holds global granule g ^ (row&7).
  const int rA = tid >> 4, gA = tid & 15;
  const float* aSrc = adj + (blockRow + rA) * (size_t)GK + k0
                      + (size_t)((gA ^ (rA & 7)) << 2);
  // B staging: thread -> row rB = tid>>3 (+64 per j), granule gB = tid&7.
  const int rB = tid >> 3, gB = tid & 7;
  const unsigned short* bSrc = Lt + (size_t)rB * GK + k0
                               + (size_t)((gB ^ (rB & 7)) << 3);

  char* AsB = (char*)As;
  char* BsB = (char*)Bs;

  const int NIT = SKK / BK;   // 64
  for (int it = 0; it < NIT; ++it) {
    const float*          ap = aSrc + (size_t)it * BK;
    const unsigned short* bp = bSrc + (size_t)it * BK;
    #pragma unroll
    for (int j = 0; j < 4; ++j)
      __builtin_amdgcn_global_load_lds(
        (const AS1 void*)(ap + (size_t)j * 32 * GK),
        (AS3 void*)(AsB + ((tid + j * 512) << 4)), 16, 0, 0);
    #pragma unroll
    for (int j = 0; j < 2; ++j)
      __builtin_amdgcn_global_load_lds(
        (const AS1 void*)(bp + (size_t)j * 64 * GK),
        (AS3 void*)(BsB + ((tid + j * 512) << 4)), 16, 0, 0);
    __syncthreads();   // drains vmcnt -> tiles visible

    #pragma unroll
    for (int ks = 0; ks < 2; ++ks) {
      s8v bfr[2];
      #pragma unroll
      for (int n = 0; n < 2; ++n) {
        int rowb = 32*wn + 16*n + l15;
        int gb   = (4*ks + (lhi >> 3)) ^ (rowb & 7);
        bfr[n] = *(const s8v*)(BsB + rowb * 128 + (gb << 4));
      }
      #pragma unroll
      for (int m = 0; m < 4; ++m) {
        int rowa = 64*wr + 16*m + l15;
        int ga0  = 8*ks + (lhi >> 2);                  // even
        int sw   = rowa & 7;
        f4v x0 = *(const f4v*)(AsB + rowa * 256 + ((ga0       ^ sw) << 4));
        f4v x1 = *(const f4v*)(AsB + rowa * 256 + (((ga0 + 1) ^ sw) << 4));
        union { unsigned u[4]; s8v v; } ua;
        ua.u[0] = cvtpk(x0[0], x0[1]);
        ua.u[1] = cvtpk(x0[2], x0[3]);
        ua.u[2] = cvtpk(x1[0], x1[1]);
        ua.u[3] = cvtpk(x1[2], x1[3]);
        acc[m][0] = __builtin_amdgcn_mfma_f32_16x16x32_bf16(ua.v, bfr[0], acc[m][0], 0, 0, 0);
        acc[m][1] = __builtin_amdgcn_mfma_f32_16x16x32_bf16(ua.v, bfr[1], acc[m][1], 0, 0, 0);
      }
    }
    __syncthreads();   // protect buffer before next overwrite
  }

  // epilogue: C/D layout col = lane&15, row = (lane>>4)*4 + r
  float* mp = Mpart + (size_t)split * GN * GD;
  #pragma unroll
  for (int m = 0; m < 4; ++m)
    #pragma unroll
    for (int n = 0; n < 2; ++n) {
      size_t r0 = blockRow + 64*wr + 16*m + ((lane >> 4) << 2);
      int    c0 = 32*wn + 16*n + l15;
      #pragma unroll
      for (int j = 0; j < 4; ++j)
        mp[(r0 + j) * GD + c0] = acc[m][n][j];
    }
}

// -- kernel 4: reduce 4 partials, out = exp(log(exp(M)) + L) -> bf16 ---------
__global__ void k_maps(const float* __restrict__ Mp, const float* __restrict__ Lf,
                       unsigned short* __restrict__ outB) {
  int row  = (blockIdx.x << 2) + (threadIdx.x >> 6);
  int lane = threadIdx.x & 63;
  size_t base = ((size_t)row << 7) + (lane << 1);
  const size_t PS = (size_t)GN * GD;
  float2 m0 = *(const float2*)(Mp + base);
  float2 m1 = *(const float2*)(Mp + PS + base);
  float2 m2 = *(const float2*)(Mp + 2*PS + base);
  float2 m3 = *(const float2*)(Mp + 3*PS + base);
  float mvx = (m0.x + m1.x) + (m2.x + m3.x);
  float mvy = (m0.y + m1.y) + (m2.y + m3.y);
  float2 lv = *(const float2*)(Lf + base);
  float v0 = (lane == 0) ? 0.f : mvx;
  float v1 = mvy;
  float nv = fmaxf(sqrtf(waveAllSum(v0*v0 + v1*v1)), 1e-7f);
  float ch = coshf(nv), sh = sinhf(nv);
  float g0 = sh * v0 / nv, g1 = sh * v1 / nv;          // agg[...,1:]
  float ny = fmaxf(sqrtf(waveAllSum(g0*g0 + g1*g1)), 1e-7f);
  float z  = fmaxf(ch, 1.f + 1e-7f);
  float th = logf(z + sqrtf(z*z - 1.f));
  float la0 = th * g0 / ny, la1 = th * g1 / ny;        // log_map(agg)
  float s0 = la0 + lv.x, s1 = la1 + lv.y;              // + (1+eps)*L
  if (lane == 0) s0 = 0.f;
  float ns  = fmaxf(sqrtf(waveAllSum(s0*s0 + s1*s1)), 1e-7f);
  float ch2 = coshf(ns), sh2 = sinhf(ns);
  float o0 = sh2 * s0 / ns, o1 = sh2 * s1 / ns;
  if (lane == 0) o0 = ch2;                             // out[...,0] = cosh
  unsigned pack = (unsigned)f2bf(o0) | ((unsigned)f2bf(o1) << 16);
  *(unsigned*)(outB + base) = pack;
}

// ---- kernel 5: T = relu(out@W1 + b1) @ W2 + b2  (bf16 MFMA, f32 accum) -----
#define PAD1 136
#define PADH 520
__global__ __launch_bounds__(256, 2) void k_mlp(const unsigned short* __restrict__ outB,
    const unsigned short* __restrict__ W1t, const float* __restrict__ b1,
    const unsigned short* __restrict__ W2t, const float* __restrict__ b2,
    float* __restrict__ Tout) {
  __shared__ __align__(16) short sA[32 * PAD1];
  __shared__ __align__(16) short sH[32 * PADH];
  const int tid  = threadIdx.x;
  const int lane = tid & 63, wc = tid >> 6;
  const int row0 = blockIdx.x << 5;

  {
    const int r = tid >> 3, cg = (tid & 7) << 4;
    const unsigned short* src = outB + (size_t)(row0 + r) * GD + cg;
    i4v v0 = ((const i4v*)src)[0];
    i4v v1 = ((const i4v*)src)[1];
    *(i4v*)&sA[r * PAD1 + cg]     = v0;
    *(i4v*)&sA[r * PAD1 + cg + 8] = v1;
  }
  __syncthreads();

  f4v acc1[2][8];
  #pragma unroll
  for (int mi = 0; mi < 2; ++mi)
    #pragma unroll
    for (int ni = 0; ni < 8; ++ni) acc1[mi][ni] = (f4v){0.f,0.f,0.f,0.f};

  const int afr = (lane & 15) * PAD1 + ((lane >> 4) << 3);
  #pragma unroll
  for (int kk = 0; kk < 4; ++kk) {                   // K = 128 d
    s8v a0 = *(const s8v*)&sA[afr + kk*32];
    s8v a1 = *(const s8v*)&sA[afr + 16*PAD1 + kk*32];
    #pragma unroll
    for (int ni = 0; ni < 8; ++ni) {
      const unsigned short* bp = W1t + (size_t)(128*wc + 16*ni + (lane & 15)) * GD
                                 + ((lane >> 4) << 3) + kk*32;
      s8v b = *(const s8v*)bp;
      acc1[0][ni] = __builtin_amdgcn_mfma_f32_16x16x32_bf16(a0, b, acc1[0][ni], 0, 0, 0);
      acc1[1][ni] = __builtin_amdgcn_mfma_f32_16x16x32_bf16(a1, b, acc1[1][ni], 0, 0, 0);
    }
  }
  #pragma unroll
  for (int ni = 0; ni < 8; ++ni) {
    int col = 128*wc + 16*ni + (lane & 15);
    float bb = b1[col];
    #pragma unroll
    for (int mi = 0; mi < 2; ++mi) {
      #pragma unroll
      for (int j = 0; j < 4; ++j) {
        int row = 16*mi + ((lane >> 4) << 2) + j;
        float v = fmaxf(acc1[mi][ni][j] + bb, 0.f);
        sH[row * PADH + col] = (short)f2bf(v);
      }
    }
  }
  __syncthreads();

  f4v acc2[2][2];
  #pragma unroll
  for (int mi = 0; mi < 2; ++mi)
    #pragma unroll
    for (int ni = 0; ni < 2; ++ni) acc2[mi][ni] = (f4v){0.f,0.f,0.f,0.f};

  const int hfr = (lane & 15) * PADH + ((lane >> 4) << 3);
  #pragma unroll
  for (int kk = 0; kk < 16; ++kk) {                  // K = 512 h
    s8v a0 = *(const s8v*)&sH[hfr + kk*32];
    s8v a1 = *(const s8v*)&sH[hfr + 16*PADH + kk*32];
    #pragma unroll
    for (int ni = 0; ni < 2; ++ni) {
      const unsigned short* bp = W2t + (size_t)(32*wc + 16*ni + (lane & 15)) * GH
                                 + ((lane >> 4) << 3) + kk*32;
      s8v b = *(const s8v*)bp;
      acc2[0][ni] = __builtin_amdgcn_mfma_f32_16x16x32_bf16(a0, b, acc2[0][ni], 0, 0, 0);
      acc2[1][ni] = __builtin_amdgcn_mfma_f32_16x16x32_bf16(a1, b, acc2[1][ni], 0, 0, 0);
    }
  }
  #pragma unroll
  for (int mi = 0; mi < 2; ++mi)
    #pragma unroll
    for (int ni = 0; ni < 2; ++ni) {
      int c0 = 32*wc + 16*ni + (lane & 15);
      float bb = b2[c0];
      size_t r0 = row0 + 16*mi + ((lane >> 4) << 2);
      #pragma unroll
      for (int j = 0; j < 4; ++j)
        Tout[(r0 + j) * GD + c0] = acc2[mi][ni][j] + bb;
    }
}

extern "C" void kernel_launch(void* const* d_in, const int* in_sizes, int n_in,
                              void* d_out, int out_size, void* d_ws, size_t ws_size,
                              hipStream_t stream) {
  const float* x   = (const float*)d_in[0];
  const float* adj = (const float*)d_in[1];
  const float* W1  = (const float*)d_in[2];
  const float* b1  = (const float*)d_in[3];
  const float* W2  = (const float*)d_in[4];
  const float* b2  = (const float*)d_in[5];
  float* Tout = (float*)d_out;

  char* ws = (char*)d_ws;
  float*          Lf    = (float*)ws;                               // [0, 8MB)
  unsigned short* Lt    = (unsigned short*)(ws + (8u  << 20));      // [8MB, 12MB)
  float*          Mpart = (float*)(ws + (12u << 20));               // [12MB, 44MB)
  unsigned short* outB  = (unsigned short*)(ws + (44u << 20));      // [44MB, 48MB)
  unsigned short* W1t   = (unsigned short*)(ws + (48u << 20));               // 128 KB
  unsigned short* W2t   = (unsigned short*)(ws + (48u << 20) + (128u << 10)); // 128 KB

  k_logmap <<<GN / 4, 256, 0, stream>>>(x, Lf);
  k_tconv  <<<dim3(GK / 64, GD / 64), 256, 0, stream>>>(Lf, Lt, GN, GD);   // L -> Lt[d][k]
  k_tconv  <<<dim3(GD / 64, GH / 64), 256, 0, stream>>>(W1, W1t, GD, GH);  // W1 -> W1t[h][d]
  k_tconv  <<<dim3(GH / 64, GD / 64), 256, 0, stream>>>(W2, W2t, GH, GD);  // W2 -> W2t[d][h]
  k_gemm   <<<(GN / BM) * SPLITS, 512, 0, stream>>>(adj, Lt, Mpart);
  k_maps   <<<GN / 4, 256, 0, stream>>>(Mpart, Lf, outB);
  k_mlp    <<<GN / 32, 256, 0, stream>>>(outB, W1t, b1, W2t, b2, Tout);
}

// Round 9
// 255.049 us; speedup vs baseline: 1.7964x; 1.0771x over previous
//
#include <hip/hip_runtime.h>

#define GN 16384
#define GD 128
#define GH 512
#define GK 16384

#define SPLITS 2
#define SKK (GK / SPLITS)   // 8192 k per split
#define BM 64
#define BK 64

typedef __attribute__((ext_vector_type(8))) short s8v;   // 8 x bf16 (as short)
typedef __attribute__((ext_vector_type(4))) float f4v;
typedef __attribute__((ext_vector_type(4))) int   i4v;

#define AS1 __attribute__((address_space(1)))
#define AS3 __attribute__((address_space(3)))

static __device__ inline unsigned short f2bf(float f) {
  union { float f; unsigned u; } a; a.f = f;
  unsigned r = a.u + 0x7fffu + ((a.u >> 16) & 1u);   // RNE
  return (unsigned short)(r >> 16);
}

static __device__ inline unsigned cvtpk(float lo, float hi) {
  unsigned r;
  asm("v_cvt_pk_bf16_f32 %0, %1, %2" : "=v"(r) : "v"(lo), "v"(hi));
  return r;
}

static __device__ inline float waveAllSum(float v) {
  #pragma unroll
  for (int off = 32; off; off >>= 1) v += __shfl_xor(v, off);
  return v;
}

// ---------------- kernel 1: L = log_map_zero(exp_map_zero(x)) ----------------
__global__ void k_logmap(const float* __restrict__ x, float* __restrict__ Lf) {
  int row  = (blockIdx.x << 2) + (threadIdx.x >> 6);
  int lane = threadIdx.x & 63;
  size_t base = ((size_t)row << 7) + (lane << 1);
  float2 v = *(const float2*)(x + base);
  float a0 = (lane == 0) ? 0.f : v.x;   // u[...,0] is ignored by exp_map
  float a1 = v.y;
  float n = fmaxf(sqrtf(waveAllSum(a0*a0 + a1*a1)), 1e-7f);
  float sh = sinhf(n), ch = coshf(n);
  float y0 = sh * a0 / n, y1 = sh * a1 / n;        // h[...,1:]
  float ny = fmaxf(sqrtf(waveAllSum(y0*y0 + y1*y1)), 1e-7f);
  float z  = fmaxf(ch, 1.f + 1e-7f);
  float th = logf(z + sqrtf(z*z - 1.f));           // arcosh(h0)
  float l0 = th * y0 / ny;
  float l1 = th * y1 / ny;
  if (lane == 0) l0 = 0.f;                         // L[...,0] = 0
  *(float2*)(Lf + base) = make_float2(l0, l1);
}

// -------- generic 64x64 tiled transpose+bf16: dst[c][r] = bf16(src[r][c]) ---
__global__ void k_tconv(const float* __restrict__ src, unsigned short* __restrict__ dst,
                        int NR, int NC) {
  __shared__ float tile[64][65];
  const int r0 = blockIdx.x << 6;
  const int c0 = blockIdx.y << 6;
  const int t  = threadIdx.x;
  const int r  = t >> 2;
  const int cg = (t & 3) << 4;
  const float* s = src + (size_t)(r0 + r) * NC + c0 + cg;
  #pragma unroll
  for (int j = 0; j < 4; ++j) {
    float4 f = ((const float4*)s)[j];
    tile[r][cg + 4*j + 0] = f.x;
    tile[r][cg + 4*j + 1] = f.y;
    tile[r][cg + 4*j + 2] = f.z;
    tile[r][cg + 4*j + 3] = f.w;
  }
  __syncthreads();
  s8v o0, o1;
  #pragma unroll
  for (int j = 0; j < 8; ++j) o0[j] = (short)f2bf(tile[cg + j][r]);
  #pragma unroll
  for (int j = 0; j < 8; ++j) o1[j] = (short)f2bf(tile[cg + 8 + j][r]);
  unsigned short* d = dst + (size_t)(c0 + r) * NR + r0 + cg;
  *(s8v*)d = o0;
  *((s8v*)d + 1) = o1;
}

// ----- kernel 3: Mpart[s] = adj[:, s] @ L[s, :]  (bf16 MFMA, f32 accum) -----
// 2-phase double-buffered global_load_lds: issue STAGE(next) BEFORE compute,
// single vmcnt(0)+barrier AFTER compute -> HBM latency hides under MFMA.
// BM=64, BK=64, 512 thr = 8 waves (2M x 4N), wave tile 32x32. LDS 64 KB
// (2 bufs x (A 16KB f32 + B 16KB bf16)) -> 2 blocks/CU. XOR-swizzled 16B
// granules both sides. A converted f32->bf16 at read via v_cvt_pk_bf16_f32.
// SPLITS=2: split = bid&1 -> each XCD one L2-resident 2 MB Lt slice.
#define ASZ (BM * BK * 4)        // 16 KB
#define BSZ (128 * BK * 2)       // 16 KB
#define BUFSZ (ASZ + BSZ)        // 32 KB
__global__ __launch_bounds__(512) void k_gemm(const float* __restrict__ adj,
    const unsigned short* __restrict__ Lt, float* __restrict__ Mpart) {
  __shared__ __align__(16) char lds[2 * BUFSZ];
  const int tid  = threadIdx.x;
  const int lane = tid & 63, wid = tid >> 6;
  const int wr = wid >> 2, wn = wid & 3;
  const int l15 = lane & 15, lhi = (lane >> 4) << 3;
  const int bid = blockIdx.x;
  const int split = bid & 1, rowblk = bid >> 1;
  const size_t blockRow = (size_t)rowblk * BM;
  const size_t k0 = (size_t)split * SKK;

  f4v acc[2][2];
  #pragma unroll
  for (int m = 0; m < 2; ++m)
    #pragma unroll
    for (int n = 0; n < 2; ++n) acc[m][n] = (f4v){0.f, 0.f, 0.f, 0.f};

  // A staging: row rA = tid>>4 (+32 per j), granule gA = tid&15.
  // LDS slot (row, g) holds global granule g ^ (row&7).
  const int rA = tid >> 4, gA = tid & 15;
  const float* aSrc = adj + (blockRow + rA) * (size_t)GK + k0
                      + (size_t)((gA ^ (rA & 7)) << 2);
  // B staging: row rB = tid>>3 (+64 per j), granule gB = tid&7.
  const int rB = tid >> 3, gB = tid & 7;
  const unsigned short* bSrc = Lt + (size_t)rB * GK + k0
                               + (size_t)((gB ^ (rB & 7)) << 3);

  const int NIT = SKK / BK;   // 128

#define STAGE(c, itv)                                                          \
  {                                                                            \
    const float*          ap = aSrc + (size_t)(itv) * BK;                      \
    const unsigned short* bp = bSrc + (size_t)(itv) * BK;                      \
    char* ab = lds + (c) * BUFSZ;                                              \
    char* bb = lds + (c) * BUFSZ + ASZ;                                        \
    _Pragma("unroll")                                                          \
    for (int j = 0; j < 2; ++j)                                                \
      __builtin_amdgcn_global_load_lds(                                        \
        (const AS1 void*)(ap + (size_t)j * 32 * GK),                           \
        (AS3 void*)(ab + ((tid + j * 512) << 4)), 16, 0, 0);                   \
    _Pragma("unroll")                                                          \
    for (int j = 0; j < 2; ++j)                                                \
      __builtin_amdgcn_global_load_lds(                                        \
        (const AS1 void*)(bp + (size_t)j * 64 * GK),                           \
        (AS3 void*)(bb + ((tid + j * 512) << 4)), 16, 0, 0);                   \
  }

  int cur = 0;
  STAGE(0, 0);
  __syncthreads();

  for (int it = 0; it < NIT; ++it) {
    if (it + 1 < NIT) STAGE(cur ^ 1, it + 1);

    const char* ab = lds + cur * BUFSZ;
    const char* bb = lds + cur * BUFSZ + ASZ;
    #pragma unroll
    for (int ks = 0; ks < 2; ++ks) {
      s8v bfr[2];
      #pragma unroll
      for (int n = 0; n < 2; ++n) {
        int rowb = 32*wn + 16*n + l15;
        int gb   = (4*ks + (lhi >> 3)) ^ (rowb & 7);
        bfr[n] = *(const s8v*)(bb + rowb * 128 + (gb << 4));
      }
      #pragma unroll
      for (int m = 0; m < 2; ++m) {
        int rowa = 32*wr + 16*m + l15;
        int ga0  = 8*ks + (lhi >> 2);
        int sw   = rowa & 7;
        f4v x0 = *(const f4v*)(ab + rowa * 256 + ((ga0       ^ sw) << 4));
        f4v x1 = *(const f4v*)(ab + rowa * 256 + (((ga0 + 1) ^ sw) << 4));
        union { unsigned u[4]; s8v v; } ua;
        ua.u[0] = cvtpk(x0[0], x0[1]);
        ua.u[1] = cvtpk(x0[2], x0[3]);
        ua.u[2] = cvtpk(x1[0], x1[1]);
        ua.u[3] = cvtpk(x1[2], x1[3]);
        acc[m][0] = __builtin_amdgcn_mfma_f32_16x16x32_bf16(ua.v, bfr[0], acc[m][0], 0, 0, 0);
        acc[m][1] = __builtin_amdgcn_mfma_f32_16x16x32_bf16(ua.v, bfr[1], acc[m][1], 0, 0, 0);
      }
    }
    __syncthreads();   // drains vmcnt (next tile arrived) + lgkm, swap-safe
    cur ^= 1;
  }
#undef STAGE

  // epilogue: C/D layout col = lane&15, row = (lane>>4)*4 + r
  float* mp = Mpart + (size_t)split * GN * GD;
  #pragma unroll
  for (int m = 0; m < 2; ++m)
    #pragma unroll
    for (int n = 0; n < 2; ++n) {
      size_t r0 = blockRow + 32*wr + 16*m + ((lane >> 4) << 2);
      int    c0 = 32*wn + 16*n + l15;
      #pragma unroll
      for (int j = 0; j < 4; ++j)
        mp[(r0 + j) * GD + c0] = acc[m][n][j];
    }
}

// -- kernel 4: reduce 2 partials, out = exp(log(exp(M)) + L) -> bf16 ---------
__global__ void k_maps(const float* __restrict__ Mp, const float* __restrict__ Lf,
                       unsigned short* __restrict__ outB) {
  int row  = (blockIdx.x << 2) + (threadIdx.x >> 6);
  int lane = threadIdx.x & 63;
  size_t base = ((size_t)row << 7) + (lane << 1);
  const size_t PS = (size_t)GN * GD;
  float2 m0 = *(const float2*)(Mp + base);
  float2 m1 = *(const float2*)(Mp + PS + base);
  float mvx = m0.x + m1.x;
  float mvy = m0.y + m1.y;
  float2 lv = *(const float2*)(Lf + base);
  float v0 = (lane == 0) ? 0.f : mvx;
  float v1 = mvy;
  float nv = fmaxf(sqrtf(waveAllSum(v0*v0 + v1*v1)), 1e-7f);
  float ch = coshf(nv), sh = sinhf(nv);
  float g0 = sh * v0 / nv, g1 = sh * v1 / nv;          // agg[...,1:]
  float ny = fmaxf(sqrtf(waveAllSum(g0*g0 + g1*g1)), 1e-7f);
  float z  = fmaxf(ch, 1.f + 1e-7f);
  float th = logf(z + sqrtf(z*z - 1.f));
  float la0 = th * g0 / ny, la1 = th * g1 / ny;        // log_map(agg)
  float s0 = la0 + lv.x, s1 = la1 + lv.y;              // + (1+eps)*L
  if (lane == 0) s0 = 0.f;
  float ns  = fmaxf(sqrtf(waveAllSum(s0*s0 + s1*s1)), 1e-7f);
  float ch2 = coshf(ns), sh2 = sinhf(ns);
  float o0 = sh2 * s0 / ns, o1 = sh2 * s1 / ns;
  if (lane == 0) o0 = ch2;                             // out[...,0] = cosh
  unsigned pack = (unsigned)f2bf(o0) | ((unsigned)f2bf(o1) << 16);
  *(unsigned*)(outB + base) = pack;
}

// ---- kernel 5: T = relu(out@W1 + b1) @ W2 + b2  (bf16 MFMA, f32 accum) -----
#define PAD1 136
#define PADH 520
__global__ __launch_bounds__(256, 2) void k_mlp(const unsigned short* __restrict__ outB,
    const unsigned short* __restrict__ W1t, const float* __restrict__ b1,
    const unsigned short* __restrict__ W2t, const float* __restrict__ b2,
    float* __restrict__ Tout) {
  __shared__ __align__(16) short sA[32 * PAD1];
  __shared__ __align__(16) short sH[32 * PADH];
  const int tid  = threadIdx.x;
  const int lane = tid & 63, wc = tid >> 6;
  const int row0 = blockIdx.x << 5;

  {
    const int r = tid >> 3, cg = (tid & 7) << 4;
    const unsigned short* src = outB + (size_t)(row0 + r) * GD + cg;
    i4v v0 = ((const i4v*)src)[0];
    i4v v1 = ((const i4v*)src)[1];
    *(i4v*)&sA[r * PAD1 + cg]     = v0;
    *(i4v*)&sA[r * PAD1 + cg + 8] = v1;
  }
  __syncthreads();

  f4v acc1[2][8];
  #pragma unroll
  for (int mi = 0; mi < 2; ++mi)
    #pragma unroll
    for (int ni = 0; ni < 8; ++ni) acc1[mi][ni] = (f4v){0.f,0.f,0.f,0.f};

  const int afr = (lane & 15) * PAD1 + ((lane >> 4) << 3);
  #pragma unroll
  for (int kk = 0; kk < 4; ++kk) {                   // K = 128 d
    s8v a0 = *(const s8v*)&sA[afr + kk*32];
    s8v a1 = *(const s8v*)&sA[afr + 16*PAD1 + kk*32];
    #pragma unroll
    for (int ni = 0; ni < 8; ++ni) {
      const unsigned short* bp = W1t + (size_t)(128*wc + 16*ni + (lane & 15)) * GD
                                 + ((lane >> 4) << 3) + kk*32;
      s8v b = *(const s8v*)bp;
      acc1[0][ni] = __builtin_amdgcn_mfma_f32_16x16x32_bf16(a0, b, acc1[0][ni], 0, 0, 0);
      acc1[1][ni] = __builtin_amdgcn_mfma_f32_16x16x32_bf16(a1, b, acc1[1][ni], 0, 0, 0);
    }
  }
  #pragma unroll
  for (int ni = 0; ni < 8; ++ni) {
    int col = 128*wc + 16*ni + (lane & 15);
    float bb = b1[col];
    #pragma unroll
    for (int mi = 0; mi < 2; ++mi) {
      #pragma unroll
      for (int j = 0; j < 4; ++j) {
        int row = 16*mi + ((lane >> 4) << 2) + j;
        float v = fmaxf(acc1[mi][ni][j] + bb, 0.f);
        sH[row * PADH + col] = (short)f2bf(v);
      }
    }
  }
  __syncthreads();

  f4v acc2[2][2];
  #pragma unroll
  for (int mi = 0; mi < 2; ++mi)
    #pragma unroll
    for (int ni = 0; ni < 2; ++ni) acc2[mi][ni] = (f4v){0.f,0.f,0.f,0.f};

  const int hfr = (lane & 15) * PADH + ((lane >> 4) << 3);
  #pragma unroll
  for (int kk = 0; kk < 16; ++kk) {                  // K = 512 h
    s8v a0 = *(const s8v*)&sH[hfr + kk*32];
    s8v a1 = *(const s8v*)&sH[hfr + 16*PADH + kk*32];
    #pragma unroll
    for (int ni = 0; ni < 2; ++ni) {
      const unsigned short* bp = W2t + (size_t)(32*wc + 16*ni + (lane & 15)) * GH
                                 + ((lane >> 4) << 3) + kk*32;
      s8v b = *(const s8v*)bp;
      acc2[0][ni] = __builtin_amdgcn_mfma_f32_16x16x32_bf16(a0, b, acc2[0][ni], 0, 0, 0);
      acc2[1][ni] = __builtin_amdgcn_mfma_f32_16x16x32_bf16(a1, b, acc2[1][ni], 0, 0, 0);
    }
  }
  #pragma unroll
  for (int mi = 0; mi < 2; ++mi)
    #pragma unroll
    for (int ni = 0; ni < 2; ++ni) {
      int c0 = 32*wc + 16*ni + (lane & 15);
      float bb = b2[c0];
      size_t r0 = row0 + 16*mi + ((lane >> 4) << 2);
      #pragma unroll
      for (int j = 0; j < 4; ++j)
        Tout[(r0 + j) * GD + c0] = acc2[mi][ni][j] + bb;
    }
}

extern "C" void kernel_launch(void* const* d_in, const int* in_sizes, int n_in,
                              void* d_out, int out_size, void* d_ws, size_t ws_size,
                              hipStream_t stream) {
  const float* x   = (const float*)d_in[0];
  const float* adj = (const float*)d_in[1];
  const float* W1  = (const float*)d_in[2];
  const float* b1  = (const float*)d_in[3];
  const float* W2  = (const float*)d_in[4];
  const float* b2  = (const float*)d_in[5];
  float* Tout = (float*)d_out;

  char* ws = (char*)d_ws;
  float*          Lf    = (float*)ws;                               // [0, 8MB)
  unsigned short* Lt    = (unsigned short*)(ws + (8u  << 20));      // [8MB, 12MB)
  float*          Mpart = (float*)(ws + (12u << 20));               // [12MB, 28MB)
  unsigned short* outB  = (unsigned short*)(ws + (28u << 20));      // [28MB, 32MB)
  unsigned short* W1t   = (unsigned short*)(ws + (32u << 20));               // 128 KB
  unsigned short* W2t   = (unsigned short*)(ws + (32u << 20) + (128u << 10)); // 128 KB

  k_logmap <<<GN / 4, 256, 0, stream>>>(x, Lf);
  k_tconv  <<<dim3(GK / 64, GD / 64), 256, 0, stream>>>(Lf, Lt, GN, GD);   // L -> Lt[d][k]
  k_tconv  <<<dim3(GD / 64, GH / 64), 256, 0, stream>>>(W1, W1t, GD, GH);  // W1 -> W1t[h][d]
  k_tconv  <<<dim3(GH / 64, GD / 64), 256, 0, stream>>>(W2, W2t, GH, GD);  // W2 -> W2t[d][h]
  k_gemm   <<<(GN / BM) * SPLITS, 512, 0, stream>>>(adj, Lt, Mpart);
  k_maps   <<<GN / 4, 256, 0, stream>>>(Mpart, Lf, outB);
  k_mlp    <<<GN / 32, 256, 0, stream>>>(outB, W1t, b1, W2t, b2, Tout);
}